// Round 12
// baseline (148.151 us; speedup 1.0000x reference)
//
#include <hip/hip_runtime.h>
#include <hip/hip_cooperative_groups.h>

namespace cg = cooperative_groups;

#define S_LEN  64000
#define B_N    64
#define TPB    512
#define WPB    8                 // waves per block
#define DSTEPS 16                // steps per wave (duo transform)
#define BSTEPS (WPB * DSTEPS)    // 128 steps per block
#define NBLK   (S_LEN / BSTEPS)  // 500 blocks (2/CU co-resident)
#define NMAC   NBLK

struct Aff { float m00, m01, m10, m11, v0, v1; };

__device__ __forceinline__ Aff aff_id() {
    Aff r; r.m00 = 1.f; r.m01 = 0.f; r.m10 = 0.f; r.m11 = 1.f; r.v0 = 0.f; r.v1 = 0.f;
    return r;
}

// X ∘ Y : apply Y first, then X
__device__ __forceinline__ Aff aff_comp(const Aff& X, const Aff& Y) {
    Aff r;
    r.m00 = fmaf(X.m00, Y.m00, X.m01 * Y.m10);
    r.m01 = fmaf(X.m00, Y.m01, X.m01 * Y.m11);
    r.m10 = fmaf(X.m10, Y.m00, X.m11 * Y.m10);
    r.m11 = fmaf(X.m10, Y.m01, X.m11 * Y.m11);
    r.v0  = fmaf(X.m00, Y.v0, fmaf(X.m01, Y.v1, X.v0));
    r.v1  = fmaf(X.m10, Y.v0, fmaf(X.m11, Y.v1, X.v1));
    return r;
}

// Per-step transform: state' = A*state + c, A = 2H - I, c = 2*gHBx
__device__ __forceinline__ Aff svf_step(float g, float R, float x) {
    Aff a;
    float T  = 1.0f / fmaf(g, g + R, 1.0f);
    float gT = g * T;
    a.m00 = fmaf(2.0f, T, -1.0f);
    a.m01 = -2.0f * gT;
    a.m10 =  2.0f * gT;
    a.m11 = fmaf(2.0f, fmaf(R, gT, T), -1.0f);
    a.v0  = a.m10 * x;
    a.v1  = g * a.v0;
    return a;
}

// LDS staging, stride 7 floats -> 2 lanes/bank max (free)
__device__ __forceinline__ void aff_store_lds(float* p, const Aff& a) {
    p[0] = a.m00; p[1] = a.m01; p[2] = a.m10; p[3] = a.m11; p[4] = a.v0; p[5] = a.v1;
}
__device__ __forceinline__ Aff aff_load_lds(const float* p) {
    Aff a; a.m00 = p[0]; a.m01 = p[1]; a.m10 = p[2]; a.m11 = p[3]; a.v0 = p[4]; a.v1 = p[5];
    return a;
}
// Packed global Aff: 2 x float4 (32 B)
__device__ __forceinline__ void aff_store_g4(float4* p, const Aff& a) {
    p[0] = make_float4(a.m00, a.m01, a.m10, a.m11);
    p[1] = make_float4(a.v0,  a.v1,  0.f,   0.f);
}
__device__ __forceinline__ Aff aff_load_g4(const float4* p) {
    float4 x = p[0], y = p[1];
    Aff a; a.m00 = x.x; a.m01 = x.y; a.m10 = x.z; a.m11 = x.w; a.v0 = y.x; a.v1 = y.y;
    return a;
}

// ---- Phase 1a: wave w composes its 16-step duo (two ILP-2 8-chains) ----
__device__ __forceinline__ void p1_micros(float* duos,
    const float* __restrict__ audio, const float* __restrict__ g,
    const float* __restrict__ twoR, int blk, int tid)
{
    const int b = tid & 63, w = tid >> 6;
    const int base = (blk * BSTEPS + w * DSTEPS) * B_N + b;
    Aff lo = aff_id(), hi = aff_id();
#pragma unroll
    for (int i = 0; i < DSTEPS / 2; ++i) {
        const int i0 = base + i * B_N;
        const int i1 = base + (i + DSTEPS / 2) * B_N;
        lo = aff_comp(svf_step(g[i0], twoR[i0], audio[i0]), lo);
        hi = aff_comp(svf_step(g[i1], twoR[i1], audio[i1]), hi);
    }
    aff_store_lds(&duos[(w * B_N + b) * 7], aff_comp(hi, lo));
}

// ---- Phase 1b (after barrier): threads 0..63 compose + write macro ----
__device__ __forceinline__ void p1_write(const float* duos,
    float4* __restrict__ wsMac, int blk, int tid)
{
    if (tid < B_N) {
        const int b = tid;
        Aff M = aff_load_lds(&duos[b * 7]);
#pragma unroll
        for (int j = 1; j < WPB; ++j)
            M = aff_comp(aff_load_lds(&duos[(j * B_N + b) * 7]), M);
        aff_store_g4(&wsMac[((long)b * NMAC + blk) * 2], M);
    }
}

// ---- Phase 2: block b scans the 500 macros of batch b (contiguous) ----
__device__ __forceinline__ void p2_scan(Aff* wt,
    const float4* __restrict__ wsMac, float2* __restrict__ sEntry,
    int b, int tid)
{
    const int lane = tid & 63, wave = tid >> 6;
    Aff acc = (tid < NMAC) ? aff_load_g4(&wsMac[((long)b * NMAC + tid) * 2])
                           : aff_id();
#pragma unroll
    for (int d = 1; d < 64; d <<= 1) {
        Aff o;
        o.m00 = __shfl_up(acc.m00, (unsigned)d, 64);
        o.m01 = __shfl_up(acc.m01, (unsigned)d, 64);
        o.m10 = __shfl_up(acc.m10, (unsigned)d, 64);
        o.m11 = __shfl_up(acc.m11, (unsigned)d, 64);
        o.v0  = __shfl_up(acc.v0,  (unsigned)d, 64);
        o.v1  = __shfl_up(acc.v1,  (unsigned)d, 64);
        if (lane >= d) acc = aff_comp(acc, o);
    }
    if (lane == 63) wt[wave] = acc;
    __syncthreads();
    if (wave == 0 && lane < WPB) {
        Aff a = wt[lane];
#pragma unroll
        for (int d = 1; d < WPB; d <<= 1) {
            Aff o;
            o.m00 = __shfl_up(a.m00, (unsigned)d, 64);
            o.m01 = __shfl_up(a.m01, (unsigned)d, 64);
            o.m10 = __shfl_up(a.m10, (unsigned)d, 64);
            o.m11 = __shfl_up(a.m11, (unsigned)d, 64);
            o.v0  = __shfl_up(a.v0,  (unsigned)d, 64);
            o.v1  = __shfl_up(a.v1,  (unsigned)d, 64);
            if (lane >= d) a = aff_comp(a, o);
        }
        wt[lane] = a;
    }
    __syncthreads();
    if (tid < NMAC) {
        Aff E;
        E.m00 = __shfl_up(acc.m00, 1u, 64);
        E.m01 = __shfl_up(acc.m01, 1u, 64);
        E.m10 = __shfl_up(acc.m10, 1u, 64);
        E.m11 = __shfl_up(acc.m11, 1u, 64);
        E.v0  = __shfl_up(acc.v0,  1u, 64);
        E.v1  = __shfl_up(acc.v1,  1u, 64);
        if (lane == 0) E = aff_id();
        if (wave > 0) E = aff_comp(E, wt[wave - 1]);
        sEntry[(long)tid * B_N + b] =
            make_float2(E.m00 + E.m01 + E.v0, E.m10 + E.m11 + E.v1);
    }
}

// ---- Phase 3: per-wave prefix from resident duos; 16-step replay; two
// 64-step transpose rounds with 256 B-coalesced stores ----
__device__ __forceinline__ void p3_replay(const float* duos, float* tile,
    const float* __restrict__ audio, const float* __restrict__ g,
    const float* __restrict__ twoR, const float* __restrict__ mix,
    const float2* __restrict__ sEntry, float* __restrict__ out,
    int blk, int tid)
{
    const int b = tid & 63, w = tid >> 6;
    float2 sm = sEntry[(long)blk * B_N + b];
    Aff P = aff_id();
    for (int j = 0; j < w; ++j)
        P = aff_comp(aff_load_lds(&duos[(j * B_N + b) * 7]), P);
    float s0 = fmaf(P.m00, sm.x, fmaf(P.m01, sm.y, P.v0));
    float s1 = fmaf(P.m10, sm.x, fmaf(P.m11, sm.y, P.v1));

    const float3* mix3 = (const float3*)mix;
    const int base = (blk * BSTEPS + w * DSTEPS) * B_N + b;

    for (int rnd = 0; rnd < 2; ++rnd) {
        if ((w >> 2) == rnd) {
#pragma unroll
            for (int i = 0; i < DSTEPS; ++i) {
                const int idx = base + i * B_N;
                float gg = g[idx], R = twoR[idx], x = audio[idx];
                float3 m = mix3[idx];
                float T  = 1.0f / fmaf(gg, gg + R, 1.0f);
                float gT = gg * T;
                float b0 = gT * x;
                float b1 = gg * b0;
                float Y0 = fmaf(T, s0, fmaf(-gT, s1, b0));
                float Y1 = fmaf(gT, s0, fmaf(fmaf(R, gT, T), s1, b1));
                s0 = fmaf(2.0f, Y0, -s0);
                s1 = fmaf(2.0f, Y1, -s1);
                float yh = x - fmaf(R, Y0, Y1);
                float y  = fmaf(R * m.x, Y0, fmaf(m.y, Y1, m.z * yh));
                tile[((w & 3) * DSTEPS + i) * 65 + b] = y;
            }
        }
        __syncthreads();
        const int col = tid & 63, row0 = tid >> 6;
        const int colbase = blk * BSTEPS + rnd * 64;
#pragma unroll
        for (int row = row0; row < B_N; row += WPB)
            out[(long)row * S_LEN + colbase + col] = tile[col * 65 + row];
        if (rnd == 0) __syncthreads();
    }
}

// ---- Fused persistent kernel (coop) ----
__global__ __launch_bounds__(TPB, 4) void k_fused(
    const float* __restrict__ audio, const float* __restrict__ g,
    const float* __restrict__ twoR, const float* __restrict__ mix,
    float4* __restrict__ wsMac, float2* __restrict__ sEntry,
    float* __restrict__ out)
{
    __shared__ float duos[WPB * B_N * 7];   // 14.3 KB, persists to phase 3
    __shared__ float tile[64 * 65];         // 16.6 KB
    __shared__ Aff   wt[WPB];

    const int tid = threadIdx.x, blk = blockIdx.x;

    p1_micros(duos, audio, g, twoR, blk, tid);
    __syncthreads();
    p1_write(duos, wsMac, blk, tid);

    cg::grid_group grid = cg::this_grid();
    grid.sync();
    if (blk < B_N) p2_scan(wt, wsMac, sEntry, blk, tid);
    grid.sync();

    p3_replay(duos, tile, audio, g, twoR, mix, sEntry, out, blk, tid);
}

// ---- Standalone fallback kernels (same device code) ----
__global__ __launch_bounds__(TPB, 4) void k_macro(
    const float* __restrict__ audio, const float* __restrict__ g,
    const float* __restrict__ twoR, float4* __restrict__ wsMac)
{
    __shared__ float duos[WPB * B_N * 7];
    p1_micros(duos, audio, g, twoR, blockIdx.x, threadIdx.x);
    __syncthreads();
    p1_write(duos, wsMac, blockIdx.x, threadIdx.x);
}

__global__ __launch_bounds__(TPB, 4) void k_scan(
    const float4* __restrict__ wsMac, float2* __restrict__ sEntry)
{
    __shared__ Aff wt[WPB];
    p2_scan(wt, wsMac, sEntry, blockIdx.x, threadIdx.x);
}

__global__ __launch_bounds__(TPB, 4) void k_replay(
    const float* __restrict__ audio, const float* __restrict__ g,
    const float* __restrict__ twoR, const float* __restrict__ mix,
    const float2* __restrict__ sEntry, float* __restrict__ out)
{
    __shared__ float duos[WPB * B_N * 7];
    __shared__ float tile[64 * 65];
    p1_micros(duos, audio, g, twoR, blockIdx.x, threadIdx.x);
    __syncthreads();
    p3_replay(duos, tile, audio, g, twoR, mix, sEntry, out,
              blockIdx.x, threadIdx.x);
}

extern "C" void kernel_launch(void* const* d_in, const int* in_sizes, int n_in,
                              void* d_out, int out_size, void* d_ws, size_t ws_size,
                              hipStream_t stream)
{
    const float* audio = (const float*)d_in[0];
    const float* g     = (const float*)d_in[1];
    const float* twoR  = (const float*)d_in[2];
    const float* mix   = (const float*)d_in[3];
    float* out = (float*)d_out;

    float4* wsMac  = (float4*)d_ws;                       // 64*NMAC*2 float4 (1 MB)
    float2* sEntry = (float2*)(wsMac + (long)B_N * NMAC * 2); // NMAC*64 float2 (256 KB)

    void* args[] = { (void*)&audio, (void*)&g, (void*)&twoR, (void*)&mix,
                     (void*)&wsMac, (void*)&sEntry, (void*)&out };
    hipError_t e = hipLaunchCooperativeKernel((void*)k_fused, dim3(NBLK),
                                              dim3(TPB), args, 0, stream);
    if (e != hipSuccess) {
        // deterministic fallback: same phases as separate dispatches
        k_macro <<<dim3(NBLK), dim3(TPB), 0, stream>>>(audio, g, twoR, wsMac);
        k_scan  <<<dim3(B_N),  dim3(TPB), 0, stream>>>(wsMac, sEntry);
        k_replay<<<dim3(NBLK), dim3(TPB), 0, stream>>>(audio, g, twoR, mix,
                                                       sEntry, out);
    }
}

// Round 13
// 102.141 us; speedup vs baseline: 1.4505x; 1.4505x over previous
//
#include <hip/hip_runtime.h>

#define S_LEN  64000
#define B_N    64
#define MCH    8            // steps per micro-chunk (one wave's serial chain)
#define WPB    8            // waves per block (micros per macro)
#define BSTEPS (MCH * WPB)  // 64 steps per block / macro
#define NBLK   (S_LEN / BSTEPS) // 1000 macro chunks
#define KPL    2            // macros per thread in elected scan (512*2 >= 1000)

struct Aff { float m00, m01, m10, m11, v0, v1; };

__device__ __forceinline__ Aff aff_id() {
    Aff r; r.m00 = 1.f; r.m01 = 0.f; r.m10 = 0.f; r.m11 = 1.f; r.v0 = 0.f; r.v1 = 0.f;
    return r;
}

// X ∘ Y : apply Y first, then X
__device__ __forceinline__ Aff aff_comp(const Aff& X, const Aff& Y) {
    Aff r;
    r.m00 = fmaf(X.m00, Y.m00, X.m01 * Y.m10);
    r.m01 = fmaf(X.m00, Y.m01, X.m01 * Y.m11);
    r.m10 = fmaf(X.m10, Y.m00, X.m11 * Y.m10);
    r.m11 = fmaf(X.m10, Y.m01, X.m11 * Y.m11);
    r.v0  = fmaf(X.m00, Y.v0, fmaf(X.m01, Y.v1, X.v0));
    r.v1  = fmaf(X.m10, Y.v0, fmaf(X.m11, Y.v1, X.v1));
    return r;
}

// Per-step transform: state' = A*state + c, A = 2H - I, c = 2*gHBx
__device__ __forceinline__ Aff svf_step(float g, float R, float x) {
    Aff a;
    float T  = 1.0f / fmaf(g, g + R, 1.0f);
    float gT = g * T;
    a.m00 = fmaf(2.0f, T, -1.0f);
    a.m01 = -2.0f * gT;
    a.m10 =  2.0f * gT;
    a.m11 = fmaf(2.0f, fmaf(R, gT, T), -1.0f);
    a.v0  = a.m10 * x;
    a.v1  = g * a.v0;
    return a;
}

__device__ __forceinline__ void aff_store_lds(float* p, const Aff& a) {
    p[0] = a.m00; p[1] = a.m01; p[2] = a.m10; p[3] = a.m11; p[4] = a.v0; p[5] = a.v1;
}
__device__ __forceinline__ Aff aff_load_lds(const float* p) {
    Aff a; a.m00 = p[0]; a.m01 = p[1]; a.m10 = p[2]; a.m11 = p[3]; a.v0 = p[4]; a.v1 = p[5];
    return a;
}
__device__ __forceinline__ void aff_store_g4(float4* p, const Aff& a) {
    p[0] = make_float4(a.m00, a.m01, a.m10, a.m11);
    p[1] = make_float4(a.v0,  a.v1,  0.f,   0.f);
}
__device__ __forceinline__ Aff aff_load_g4(const float4* p) {
    float4 x = p[0], y = p[1];
    Aff a; a.m00 = x.x; a.m01 = x.y; a.m10 = x.z; a.m11 = x.w; a.v0 = y.x; a.v1 = y.y;
    return a;
}

// Pass 1+2 merged: every block composes its 64-step macro and publishes it;
// the LAST 64 blocks to finish (ticket >= NBLK-64) each scan one batch's
// 1000 macros and emit per-macro entry states. wsMac layout [batch][macro].
__global__ __launch_bounds__(512, 4) void k_macscan(
    const float* __restrict__ audio, const float* __restrict__ g,
    const float* __restrict__ twoR, float4* __restrict__ wsMac,
    float2* __restrict__ sIn, int* __restrict__ ctr)
{
    __shared__ float affs[WPB * B_N * 7];   // 14.3 KB micro staging
    __shared__ Aff wt[WPB];
    __shared__ int shInfo;
    const int tid = threadIdx.x;
    const int b   = tid & 63;
    const int w   = tid >> 6;
    const int blk = blockIdx.x;
    const int base = (blk * BSTEPS + w * MCH) * B_N + b;

    // ---- macro phase (identical math to R10 k_macro) ----
    Aff acc = aff_id();
#pragma unroll
    for (int i = 0; i < MCH; ++i) {
        const int idx = base + i * B_N;
        acc = aff_comp(svf_step(g[idx], twoR[idx], audio[idx]), acc);
    }
    aff_store_lds(&affs[(w * B_N + b) * 7], acc);
    __syncthreads();

    if (w == 0) {
        Aff M = acc;
#pragma unroll
        for (int j = 1; j < WPB; ++j)
            M = aff_comp(aff_load_lds(&affs[(j * B_N + b) * 7]), M);
        aff_store_g4(&wsMac[((long)b * NBLK + blk) * 2], M);
        __threadfence();   // publish macro (device scope) before ticket
    }
    __syncthreads();

    // ---- election: last 64 finishers become scanners ----
    if (tid == 0)
        shInfo = __hip_atomic_fetch_add(ctr, 1, __ATOMIC_ACQ_REL,
                                        __HIP_MEMORY_SCOPE_AGENT);
    __syncthreads();
    const int ticket = shInfo;
    if (ticket < NBLK - B_N) return;        // not elected
    const int sb = ticket - (NBLK - B_N);   // scan batch 0..63

    // wait for all macros (short spin: we were among the last to finish)
    if (tid == 0) {
        while (__hip_atomic_load(ctr, __ATOMIC_ACQUIRE,
                                 __HIP_MEMORY_SCOPE_AGENT) < NBLK)
            __builtin_amdgcn_s_sleep(8);
        shInfo = 1;
    }
    __syncthreads();

    // ---- scan phase: 512 threads, thread t owns macros 2t, 2t+1 ----
    const int lane = tid & 63, wave = tid >> 6;
    Aff c0 = aff_id(), c1 = aff_id();
    if (2 * tid < NBLK) {
        const float4* src = &wsMac[((long)sb * NBLK + 2 * tid) * 2];
        c0 = aff_load_g4(src);
        if (2 * tid + 1 < NBLK) c1 = aff_load_g4(src + 2);
    }
    Aff acc2 = aff_comp(c1, c0);

    // wave-inclusive Hillis-Steele scan
#pragma unroll
    for (int d = 1; d < 64; d <<= 1) {
        Aff o;
        o.m00 = __shfl_up(acc2.m00, (unsigned)d, 64);
        o.m01 = __shfl_up(acc2.m01, (unsigned)d, 64);
        o.m10 = __shfl_up(acc2.m10, (unsigned)d, 64);
        o.m11 = __shfl_up(acc2.m11, (unsigned)d, 64);
        o.v0  = __shfl_up(acc2.v0,  (unsigned)d, 64);
        o.v1  = __shfl_up(acc2.v1,  (unsigned)d, 64);
        if (lane >= d) acc2 = aff_comp(acc2, o);
    }
    if (lane == 63) wt[wave] = acc2;
    __syncthreads();
    if (wave == 0 && lane < WPB) {
        Aff a = wt[lane];
#pragma unroll
        for (int d = 1; d < WPB; d <<= 1) {
            Aff o;
            o.m00 = __shfl_up(a.m00, (unsigned)d, 64);
            o.m01 = __shfl_up(a.m01, (unsigned)d, 64);
            o.m10 = __shfl_up(a.m10, (unsigned)d, 64);
            o.m11 = __shfl_up(a.m11, (unsigned)d, 64);
            o.v0  = __shfl_up(a.v0,  (unsigned)d, 64);
            o.v1  = __shfl_up(a.v1,  (unsigned)d, 64);
            if (lane >= d) a = aff_comp(a, o);
        }
        wt[lane] = a;
    }
    __syncthreads();

    if (2 * tid < NBLK) {
        Aff E;
        E.m00 = __shfl_up(acc2.m00, 1u, 64);
        E.m01 = __shfl_up(acc2.m01, 1u, 64);
        E.m10 = __shfl_up(acc2.m10, 1u, 64);
        E.m11 = __shfl_up(acc2.m11, 1u, 64);
        E.v0  = __shfl_up(acc2.v0,  1u, 64);
        E.v1  = __shfl_up(acc2.v1,  1u, 64);
        if (lane == 0) E = aff_id();
        if (wave > 0) E = aff_comp(E, wt[wave - 1]);

        // entry of macro 2t: E applied to s0=(1,1)
        sIn[(2 * tid) * B_N + sb] =
            make_float2(E.m00 + E.m01 + E.v0, E.m10 + E.m11 + E.v1);
        if (2 * tid + 1 < NBLK) {
            Aff F = aff_comp(c0, E);   // prefix including macro 2t
            sIn[(2 * tid + 1) * B_N + sb] =
                make_float2(F.m00 + F.m01 + F.v0, F.m10 + F.m11 + F.v1);
        }
    }
}

// Pass 3 (byte-identical math to R10's proven k_replay; nt stores on out)
__global__ __launch_bounds__(512, 4) void k_replay(
    const float* __restrict__ audio, const float* __restrict__ g,
    const float* __restrict__ twoR, const float* __restrict__ mix,
    const float2* __restrict__ sIn, float* __restrict__ out)
{
    __shared__ float lds[BSTEPS * 65];
    const int b   = threadIdx.x & 63;
    const int w   = threadIdx.x >> 6;
    const int blk = blockIdx.x;
    const int base = (blk * BSTEPS + w * MCH) * B_N + b;

    const float3* mix3 = (const float3*)mix;
    float gv[MCH], Rv[MCH], xv[MCH];
    float3 mv[MCH];
#pragma unroll
    for (int i = 0; i < MCH; ++i) {
        const int idx = base + i * B_N;
        gv[i] = g[idx]; Rv[i] = twoR[idx]; xv[i] = audio[idx];
        mv[i] = mix3[idx];
    }

    Aff acc = aff_id();
#pragma unroll
    for (int i = 0; i < MCH; ++i)
        acc = aff_comp(svf_step(gv[i], Rv[i], xv[i]), acc);
    aff_store_lds(&lds[(w * B_N + b) * 7], acc);
    __syncthreads();

    float2 sm = sIn[blk * B_N + b];
    Aff P = aff_id();
    for (int j = 0; j < w; ++j) {
        Aff A = aff_load_lds(&lds[(j * B_N + b) * 7]);
        P = aff_comp(A, P);
    }
    float s0 = fmaf(P.m00, sm.x, fmaf(P.m01, sm.y, P.v0));
    float s1 = fmaf(P.m10, sm.x, fmaf(P.m11, sm.y, P.v1));
    __syncthreads();

#pragma unroll
    for (int i = 0; i < MCH; ++i) {
        float gg = gv[i], R = Rv[i], x = xv[i];
        float T  = 1.0f / fmaf(gg, gg + R, 1.0f);
        float gT = gg * T;
        float b0 = gT * x;
        float b1 = gg * b0;
        float Y0 = fmaf(T, s0, fmaf(-gT, s1, b0));
        float Y1 = fmaf(gT, s0, fmaf(fmaf(R, gT, T), s1, b1));
        s0 = fmaf(2.0f, Y0, -s0);
        s1 = fmaf(2.0f, Y1, -s1);

        float yh = x - fmaf(R, Y0, Y1);
        float y  = fmaf(R * mv[i].x, Y0, fmaf(mv[i].y, Y1, mv[i].z * yh));

        lds[(w * MCH + i) * 65 + b] = y;
    }
    __syncthreads();

    const int col = threadIdx.x & 63;
    const int r0  = threadIdx.x >> 6;
    const int colbase = blk * BSTEPS;
#pragma unroll
    for (int r = r0; r < B_N; r += WPB)
        __builtin_nontemporal_store(lds[col * 65 + r],
                                    &out[r * S_LEN + colbase + col]);
}

extern "C" void kernel_launch(void* const* d_in, const int* in_sizes, int n_in,
                              void* d_out, int out_size, void* d_ws, size_t ws_size,
                              hipStream_t stream)
{
    const float* audio = (const float*)d_in[0];
    const float* g     = (const float*)d_in[1];
    const float* twoR  = (const float*)d_in[2];
    const float* mix   = (const float*)d_in[3];
    float* out = (float*)d_out;

    float4* wsMac = (float4*)d_ws;                         // 64*NBLK*2 float4 (2 MB)
    float2* sIn   = (float2*)(wsMac + (long)B_N * NBLK * 2);   // NBLK*64 float2 (0.5 MB)
    int*    ctr   = (int*)(sIn + (long)NBLK * B_N);        // 1 int

    hipMemsetAsync(ctr, 0, sizeof(int), stream);   // must be 0 every call

    k_macscan<<<dim3(NBLK), dim3(512), 0, stream>>>(audio, g, twoR,
                                                    wsMac, sIn, ctr);
    k_replay <<<dim3(NBLK), dim3(512), 0, stream>>>(audio, g, twoR, mix,
                                                    sIn, out);
}

// Round 14
// 37.311 us; speedup vs baseline: 3.9707x; 2.7375x over previous
//
#include <hip/hip_runtime.h>

#define S_LEN  64000
#define B_N    64
#define MCH    8            // steps per micro-chunk (one wave's serial chain)
#define WPB    8            // waves per block (micros per macro)
#define BSTEPS (MCH * WPB)  // 64 steps per block / macro
#define NBLK   (S_LEN / BSTEPS) // 1000 macro chunks
#define SC_T   1024         // scan threads: one macro per thread (>= NBLK)

struct Aff { float m00, m01, m10, m11, v0, v1; };

__device__ __forceinline__ Aff aff_id() {
    Aff r; r.m00 = 1.f; r.m01 = 0.f; r.m10 = 0.f; r.m11 = 1.f; r.v0 = 0.f; r.v1 = 0.f;
    return r;
}

// X ∘ Y : apply Y first, then X
__device__ __forceinline__ Aff aff_comp(const Aff& X, const Aff& Y) {
    Aff r;
    r.m00 = fmaf(X.m00, Y.m00, X.m01 * Y.m10);
    r.m01 = fmaf(X.m00, Y.m01, X.m01 * Y.m11);
    r.m10 = fmaf(X.m10, Y.m00, X.m11 * Y.m10);
    r.m11 = fmaf(X.m10, Y.m01, X.m11 * Y.m11);
    r.v0  = fmaf(X.m00, Y.v0, fmaf(X.m01, Y.v1, X.v0));
    r.v1  = fmaf(X.m10, Y.v0, fmaf(X.m11, Y.v1, X.v1));
    return r;
}

// Per-step transform: state' = A*state + c, A = 2H - I, c = 2*gHBx
__device__ __forceinline__ Aff svf_step(float g, float R, float x) {
    Aff a;
    float T  = 1.0f / fmaf(g, g + R, 1.0f);
    float gT = g * T;
    a.m00 = fmaf(2.0f, T, -1.0f);
    a.m01 = -2.0f * gT;
    a.m10 =  2.0f * gT;
    a.m11 = fmaf(2.0f, fmaf(R, gT, T), -1.0f);
    a.v0  = a.m10 * x;
    a.v1  = g * a.v0;
    return a;
}

__device__ __forceinline__ void aff_store_lds(float* p, const Aff& a) {
    p[0] = a.m00; p[1] = a.m01; p[2] = a.m10; p[3] = a.m11; p[4] = a.v0; p[5] = a.v1;
}
__device__ __forceinline__ Aff aff_load_lds(const float* p) {
    Aff a; a.m00 = p[0]; a.m01 = p[1]; a.m10 = p[2]; a.m11 = p[3]; a.v0 = p[4]; a.v1 = p[5];
    return a;
}
__device__ __forceinline__ void aff_store_g4(float4* p, const Aff& a) {
    p[0] = make_float4(a.m00, a.m01, a.m10, a.m11);
    p[1] = make_float4(a.v0,  a.v1,  0.f,   0.f);
}
__device__ __forceinline__ Aff aff_load_g4(const float4* p) {
    float4 x = p[0], y = p[1];
    Aff a; a.m00 = x.x; a.m01 = x.y; a.m10 = x.z; a.m11 = x.w; a.v0 = y.x; a.v1 = y.y;
    return a;
}

// Pass 1: wave w composes 8-step micro transform (loads hoisted up front);
// block composes its 8 micros (64 steps) into one macro via LDS.
// wsMac layout [batch][macro] -> scan reads contiguous.
__global__ __launch_bounds__(512, 4) void k_macro(
    const float* __restrict__ audio, const float* __restrict__ g,
    const float* __restrict__ twoR, float4* __restrict__ wsMac)
{
    __shared__ float affs[WPB * B_N * 7];
    const int b   = threadIdx.x & 63;
    const int w   = threadIdx.x >> 6;
    const int blk = blockIdx.x;
    const int base = (blk * BSTEPS + w * MCH) * B_N + b;

    // explicit load-all first: 24 independent loads in flight
    float gv[MCH], Rv[MCH], xv[MCH];
#pragma unroll
    for (int i = 0; i < MCH; ++i) {
        const int idx = base + i * B_N;
        gv[i] = g[idx]; Rv[i] = twoR[idx]; xv[i] = audio[idx];
    }

    Aff acc = aff_id();
#pragma unroll
    for (int i = 0; i < MCH; ++i)
        acc = aff_comp(svf_step(gv[i], Rv[i], xv[i]), acc);
    aff_store_lds(&affs[(w * B_N + b) * 7], acc);
    __syncthreads();

    if (w == 0) {
        Aff M = acc;
#pragma unroll
        for (int j = 1; j < WPB; ++j)
            M = aff_comp(aff_load_lds(&affs[(j * B_N + b) * 7]), M);
        aff_store_g4(&wsMac[((long)b * NBLK + blk) * 2], M);
    }
}

// Pass 2 (identical to R10): one block per batch; thread t owns macro t.
__global__ __launch_bounds__(SC_T, 2) void k_scan(
    const float4* __restrict__ wsMac, float2* __restrict__ sIn)
{
    const int b    = blockIdx.x;
    const int t    = threadIdx.x;
    const int lane = t & 63;
    const int wave = t >> 6;

    Aff m = (t < NBLK) ? aff_load_g4(&wsMac[((long)b * NBLK + t) * 2]) : aff_id();

    Aff acc = m;
#pragma unroll
    for (int d = 1; d < 64; d <<= 1) {
        Aff o;
        o.m00 = __shfl_up(acc.m00, (unsigned)d, 64);
        o.m01 = __shfl_up(acc.m01, (unsigned)d, 64);
        o.m10 = __shfl_up(acc.m10, (unsigned)d, 64);
        o.m11 = __shfl_up(acc.m11, (unsigned)d, 64);
        o.v0  = __shfl_up(acc.v0,  (unsigned)d, 64);
        o.v1  = __shfl_up(acc.v1,  (unsigned)d, 64);
        if (lane >= d) acc = aff_comp(acc, o);
    }

    __shared__ Aff wt[SC_T / 64];
    if (lane == 63) wt[wave] = acc;
    __syncthreads();

    if (wave == 0 && lane < 16) {
        Aff a = wt[lane];
#pragma unroll
        for (int d = 1; d < 16; d <<= 1) {
            Aff o;
            o.m00 = __shfl_up(a.m00, (unsigned)d, 64);
            o.m01 = __shfl_up(a.m01, (unsigned)d, 64);
            o.m10 = __shfl_up(a.m10, (unsigned)d, 64);
            o.m11 = __shfl_up(a.m11, (unsigned)d, 64);
            o.v0  = __shfl_up(a.v0,  (unsigned)d, 64);
            o.v1  = __shfl_up(a.v1,  (unsigned)d, 64);
            if (lane >= d) a = aff_comp(a, o);
        }
        wt[lane] = a;
    }
    __syncthreads();

    if (t < NBLK) {
        Aff E;
        E.m00 = __shfl_up(acc.m00, 1u, 64);
        E.m01 = __shfl_up(acc.m01, 1u, 64);
        E.m10 = __shfl_up(acc.m10, 1u, 64);
        E.m11 = __shfl_up(acc.m11, 1u, 64);
        E.v0  = __shfl_up(acc.v0,  1u, 64);
        E.v1  = __shfl_up(acc.v1,  1u, 64);
        if (lane == 0) E = aff_id();
        if (wave > 0) E = aff_comp(E, wt[wave - 1]);

        float e0 = E.m00 + E.m01 + E.v0;
        float e1 = E.m10 + E.m11 + E.v1;
        sIn[t * B_N + b] = make_float2(e0, e1);
    }
}

// Pass 3: hold ONLY g,R,x (24 regs) -> <=64 VGPR -> 4 blocks/CU, 32 waves.
// mix streamed inside the replay loop. float4 output stores.
__global__ __launch_bounds__(512, 4) void k_replay(
    const float* __restrict__ audio, const float* __restrict__ g,
    const float* __restrict__ twoR, const float* __restrict__ mix,
    const float2* __restrict__ sIn, float* __restrict__ out)
{
    __shared__ float lds[BSTEPS * 65];  // reused: first WPB*64*7 = Aff staging
    const int b   = threadIdx.x & 63;
    const int w   = threadIdx.x >> 6;
    const int blk = blockIdx.x;
    const int base = (blk * BSTEPS + w * MCH) * B_N + b;

    float gv[MCH], Rv[MCH], xv[MCH];
#pragma unroll
    for (int i = 0; i < MCH; ++i) {
        const int idx = base + i * B_N;
        gv[i] = g[idx]; Rv[i] = twoR[idx]; xv[i] = audio[idx];
    }

    Aff acc = aff_id();
#pragma unroll
    for (int i = 0; i < MCH; ++i)
        acc = aff_comp(svf_step(gv[i], Rv[i], xv[i]), acc);
    aff_store_lds(&lds[(w * B_N + b) * 7], acc);
    __syncthreads();

    float2 sm = sIn[blk * B_N + b];
    Aff P = aff_id();
    for (int j = 0; j < w; ++j) {
        Aff A = aff_load_lds(&lds[(j * B_N + b) * 7]);
        P = aff_comp(A, P);
    }
    float s0 = fmaf(P.m00, sm.x, fmaf(P.m01, sm.y, P.v0));
    float s1 = fmaf(P.m10, sm.x, fmaf(P.m11, sm.y, P.v1));
    __syncthreads();  // prefix reads done before tile overwrites staging

    const float3* mix3 = (const float3*)mix;
#pragma unroll
    for (int i = 0; i < MCH; ++i) {
        const int idx = base + i * B_N;
        float3 m = mix3[idx];            // streamed, issued early by compiler
        float gg = gv[i], R = Rv[i], x = xv[i];
        float T  = 1.0f / fmaf(gg, gg + R, 1.0f);
        float gT = gg * T;
        float b0 = gT * x;
        float b1 = gg * b0;
        float Y0 = fmaf(T, s0, fmaf(-gT, s1, b0));
        float Y1 = fmaf(gT, s0, fmaf(fmaf(R, gT, T), s1, b1));
        s0 = fmaf(2.0f, Y0, -s0);
        s1 = fmaf(2.0f, Y1, -s1);

        float yh = x - fmaf(R, Y0, Y1);
        float y  = fmaf(R * m.x, Y0, fmaf(m.y, Y1, m.z * yh));

        lds[(w * MCH + i) * 65 + b] = y;
    }
    __syncthreads();

    // float4 stores: thread handles 4 consecutive cols of one row; each
    // 16-lane group stores 256 B contiguous. LDS reads 2-way max (free).
    const int c4 = (threadIdx.x & 15) * 4;         // col base 0..60
    const int r0 = threadIdx.x >> 4;               // row 0..31
    const long colbase = (long)blk * BSTEPS;
#pragma unroll
    for (int r = r0; r < B_N; r += 32) {
        float4 v = make_float4(lds[(c4 + 0) * 65 + r], lds[(c4 + 1) * 65 + r],
                               lds[(c4 + 2) * 65 + r], lds[(c4 + 3) * 65 + r]);
        *(float4*)&out[(long)r * S_LEN + colbase + c4] = v;
    }
}

extern "C" void kernel_launch(void* const* d_in, const int* in_sizes, int n_in,
                              void* d_out, int out_size, void* d_ws, size_t ws_size,
                              hipStream_t stream)
{
    const float* audio = (const float*)d_in[0];
    const float* g     = (const float*)d_in[1];
    const float* twoR  = (const float*)d_in[2];
    const float* mix   = (const float*)d_in[3];
    float* out = (float*)d_out;

    float4* wsMac = (float4*)d_ws;                           // 64*NBLK*2 float4 (2 MB)
    float2* sIn   = (float2*)(wsMac + (long)B_N * NBLK * 2); // NBLK*64 float2 (0.5 MB)

    k_macro <<<dim3(NBLK), dim3(512), 0, stream>>>(audio, g, twoR, wsMac);
    k_scan  <<<dim3(B_N), dim3(SC_T), 0, stream>>>(wsMac, sIn);
    k_replay<<<dim3(NBLK), dim3(512), 0, stream>>>(audio, g, twoR, mix, sIn, out);
}